// Round 14
// baseline (3189.509 us; speedup 1.0000x reference)
//
#include <hip/hip_runtime.h>

typedef __attribute__((ext_vector_type(4)))  int   int32x4;
typedef __attribute__((ext_vector_type(16))) int   int32x16;
typedef __attribute__((ext_vector_type(16))) float f32x16;
typedef unsigned char uchar;

#define HID 512
#define BT 32
#define OUTN 12

// H/O global scale: |H| ~ N(0, 1/sqrt(512)) => sigma 0.0442, 6.36-sigma = 0.281
#define SH 0.28125f
#define S_COMB (SH / 16129.0f)          // SH / 127^2

// ---- quantize into 2 signed-int8 levels: f ~= SH/127 * (q1 + q2/128)
static __device__ __forceinline__ void quant2(float f, int& q1, int& q2) {
    float h  = fminf(fmaxf(f * (1.0f / SH), -1.0f), 1.0f) * 127.0f;
    float Q1 = rintf(h);
    float r1 = (h - Q1) * 128.0f;
    float Q2 = rintf(r1);
    q1 = (int)Q1; q2 = (int)Q2;
}

// ---- pack H (fp32 [512][512]) into 2 i8 level-streams, A-frag order (A row = n):
//   Hpk[ ((w*16 + ks)*2 + L)*1024 + l*16 + j ] =
//     qL( H[n = w*32 + (l&31)][k = ks*32 + (l>>5)*16 + j] )
__global__ void pack_h(const float* __restrict__ Hw, uchar* __restrict__ Hpk) {
    int t  = blockIdx.x * blockDim.x + threadIdx.x;   // 0..32767
    int l  = t & 63;
    int L  = (t >> 6) & 1;
    int ks = (t >> 7) & 15;
    int w  = t >> 11;                                 // 0..15
    int n  = w * 32 + (l & 31);
    int k0 = ks * 32 + (l >> 5) * 16;
    uint d[4] = {0, 0, 0, 0};
#pragma unroll
    for (int j = 0; j < 16; ++j) {
        int q1, q2;
        quant2(Hw[n * HID + k0 + j], q1, q2);
        int q = L ? q2 : q1;
        d[j >> 2] |= ((uint)(q & 255)) << (8 * (j & 3));
    }
    *(uint4*)(Hpk + (size_t)t * 16) = make_uint4(d[0], d[1], d[2], d[3]);
}

// ---- pack O (fp32 [12][512]) into 2 i8 level-streams (rows padded to 16), for 16x16x64:
//   Opk[ (L*8 + ks)*1024 + l*16 + j ] = qL( O[o = l&15][k = ks*64 + (l>>4)*16 + j] )
__global__ void pack_o(const float* __restrict__ Ow, uchar* __restrict__ Opk) {
    int t  = blockIdx.x * blockDim.x + threadIdx.x;   // 0..1023
    int l  = t & 63;
    int ks = (t >> 6) & 7;
    int L  = t >> 9;                                  // 0..1
    int o  = l & 15;
    int k0 = ks * 64 + (l >> 4) * 16;
    uint d[4] = {0, 0, 0, 0};
#pragma unroll
    for (int j = 0; j < 16; ++j) {
        float f = (o < OUTN) ? Ow[o * HID + k0 + j] : 0.0f;
        int q1, q2;
        quant2(f, q1, q2);
        int q = L ? q2 : q1;
        d[j >> 2] |= ((uint)(q & 255)) << (8 * (j & 3));
    }
    *(uint4*)(Opk + (size_t)t * 16) = make_uint4(d[0], d[1], d[2], d[3]);
}

// LDS map (144 KB):
//   [0, 65536)        z: 2 dbufs x 2 level-planes [32 m][512 n] i8, XOR-swizzled
//                     byte(m,k,L) = buf*32768 + L*16384 + m*512 + (k ^ ((m&15)<<4))
//   [65536, 81920)    Opk copy (16 KB, verbatim)
//   [81920, 98304)    (unused pad)
//   [98304, 163840)   DMA ring: w*4096 + slot*1024, 4 slots/wave

// ---- output GEMM (2 rotating waves): y = sigmoid(z @ O^T + m), op from LDS
static __device__ __forceinline__ void out_gemm(const char* zr, const char* opb,
                                                const float* mbv, int wloc, int l,
                                                float* __restrict__ out,
                                                int b0, int trow, int T) {
    int32x4 aA = {0, 0, 0, 0}, aB = {0, 0, 0, 0};
    const int m     = l & 15;
    const int om    = wloc * 16 + m;       // block-local batch row in z planes
    const int obase = om * 512;
    const int oxor  = (om & 15) << 4;
    const int okb   = (l >> 4) * 16;
    const char* op  = opb + (size_t)l * 16;
#pragma unroll
    for (int ks = 0; ks < 8; ++ks) {
        int32x4 o1 = *(const int32x4*)(op + ks * 1024);
        int32x4 o2 = *(const int32x4*)(op + 8192 + ks * 1024);
        int off = obase + ((ks * 64 + okb) ^ oxor);
        int32x4 z1 = *(const int32x4*)(zr + off);
        int32x4 z2 = *(const int32x4*)(zr + 16384 + off);
        aA = __builtin_amdgcn_mfma_i32_16x16x64_i8(o1, z1, aA, 0, 0, 0);
        aB = __builtin_amdgcn_mfma_i32_16x16x64_i8(o1, z2, aB, 0, 0, 0);
        aB = __builtin_amdgcn_mfma_i32_16x16x64_i8(o2, z1, aB, 0, 0, 0);
    }
    if ((l >> 4) < 3) {
        float4 y4;
        float* yp = &y4.x;
#pragma unroll
        for (int r = 0; r < 4; ++r) {
            float logit = mbv[r] + S_COMB * ((float)aA[r] + 0.0078125f * (float)aB[r]);
            yp[r] = __fdividef(1.0f, 1.0f + __expf(-logit));
        }
        *(float4*)(out + ((size_t)(b0 + om) * T + trow) * OUTN + (l >> 4) * 4) = y4;
    }
}

// issue chunk ((S)+4)&31 into ring slot (S)&3; chunk c: ks = c>>1, level L = c&1
#define ISSUE_SITE(S)                                                                   \
    {                                                                                   \
        const int c_  = ((S) + 4) & 31;                                                 \
        const int kk_ = c_ >> 1;                                                        \
        const int LL_ = c_ & 1;                                                         \
        const uchar* g_ = Hpk + (size_t)(w * 16 + kk_) * 2048 + LL_ * 1024              \
                          + (size_t)l * 16;                                             \
        __builtin_amdgcn_global_load_lds(                                               \
            (const __attribute__((address_space(1))) uint*)g_,                          \
            (__attribute__((address_space(3))) uint*)(ringb + ((S) & 3) * 1024),        \
            16, 0, 0);                                                                  \
    }

#define WAITV2()                                                \
    asm volatile("s_waitcnt vmcnt(2)" ::: "memory");            \
    __builtin_amdgcn_sched_barrier(0)

// raw barrier: LDS ops drained, ring DMA stays in flight (no vmcnt)
#define BARRIER()                                               \
    asm volatile("s_waitcnt lgkmcnt(0)" ::: "memory");          \
    __builtin_amdgcn_s_barrier();                               \
    asm volatile("" ::: "memory");                              \
    __builtin_amdgcn_sched_barrier(0)

__launch_bounds__(1024)
__global__ void ctrnn_kernel(const float* __restrict__ x,
                             const int*   __restrict__ Tp,
                             const float* __restrict__ Iw,
                             const float* __restrict__ v,
                             const float* __restrict__ mb,
                             const uchar* __restrict__ Hpk,
                             const uchar* __restrict__ Opk,
                             float* __restrict__ out) {
    __shared__ uint4 zs4[10240];   // 160 KB declared; 144 KB used
    char* zsc = (char*)zs4;

    const int T   = Tp[0];
    const int tid = threadIdx.x;
    const int l   = tid & 63;
    const int w   = tid >> 6;                    // wave 0..15; owns n in [w*32, w*32+32)
    const int b0  = blockIdx.x * BT;

    char* ringb = zsc + 98304 + w * 4096;
    const char* opb = zsc + 65536;

    // zero z buf 0 (z_0 = 0 -> both levels 0): 32 KB
#pragma unroll
    for (int i = 0; i < 2; ++i) zs4[tid + i * 1024] = make_uint4(0, 0, 0, 0);

    // stage Opk (16 KB verbatim)
    ((uint4*)(zsc + 65536))[tid] = ((const uint4*)Opk)[tid];

    // drive: drv[r] = x[m]*Iw[n]+v[n], lane owns m = l&31, n = w*32 + nset(r)
    const float xm = x[b0 + (l & 31)];
    f32x16 drv;
#pragma unroll
    for (int r = 0; r < 16; ++r) {
        int n = w * 32 + (r & 3) + 8 * (r >> 2) + 4 * (l >> 5);
        drv[r] = fmaf(xm, Iw[n], v[n]);
    }

    // output bias per lane (loaded by ALL waves: out_gemm rotates across waves)
    float mbv[4] = {0.f, 0.f, 0.f, 0.f};
    if ((l >> 4) < 3) {
#pragma unroll
        for (int r = 0; r < 4; ++r) mbv[r] = mb[(l >> 4) * 4 + r];
    }

    // z B-frag addressing: col j = m = l&31, k = ks*32 + (l>>5)*16
    const int am    = l & 31;
    const int abase = am * 512;
    const int axor  = (am & 15) << 4;
    const int akb   = (l >> 5) * 16;

    __syncthreads();   // staging visible (full drain OK: ring not started yet)

    // ring prologue: chunks 0..3 into slots 0..3 (ISSUE_SITE(S) issues chunk (S+4)&31)
    ISSUE_SITE(28); ISSUE_SITE(29); ISSUE_SITE(30); ISSUE_SITE(31);

#pragma unroll 1
    for (int t = 0; t < T; ++t) {
        const char* zr = zsc + (t & 1) * 32768;
        char*       zw = zsc + ((t & 1) ^ 1) * 32768;

        // ---- phase 3 (2 rotating waves): y_{t-1} from z_t (current read buffer)
        if (((w & 14) == ((t & 7) * 2)) && t > 0)
            out_gemm(zr, opb, mbv, w & 1, l, out, b0, t - 1, T);

        // ---- phase 1: 3-term i8 MFMA; h1/h2 via DMA ring (4 in flight, vmcnt(2))
        int32x16 a2 = {0}, a3 = {0};
#pragma unroll
        for (int ks = 0; ks < 16; ++ks) {
            WAITV2();   // chunks 2ks, 2ks+1 landed
            int32x4 h1 = *(const int32x4*)(ringb + ((2 * ks) & 3) * 1024 + (size_t)l * 16);
            int32x4 h2 = *(const int32x4*)(ringb + ((2 * ks + 1) & 3) * 1024 + (size_t)l * 16);
            int off = abase + ((ks * 32 + akb) ^ axor);
            int32x4 z1 = *(const int32x4*)(zr + off);
            int32x4 z2 = *(const int32x4*)(zr + 16384 + off);
            a2 = __builtin_amdgcn_mfma_i32_32x32x32_i8(h1, z1, a2, 0, 0, 0);
            a3 = __builtin_amdgcn_mfma_i32_32x32x32_i8(h1, z2, a3, 0, 0, 0);
            a3 = __builtin_amdgcn_mfma_i32_32x32x32_i8(h2, z1, a3, 0, 0, 0);
            __builtin_amdgcn_sched_barrier(0);   // ring reads consumed before refill
            ISSUE_SITE(2 * ks);                  // chunk 2ks+4  (wraps to next step)
            ISSUE_SITE(2 * ks + 1);              // chunk 2ks+5
        }

        // ---- phase 2: u -> z = tanh(u) -> 2-level i8, packed b32 writes (lane-local)
        {
            const int h5 = l >> 5;
#pragma unroll
            for (int rq = 0; rq < 4; ++rq) {
                uint d1 = 0, d2 = 0;
#pragma unroll
                for (int e = 0; e < 4; ++e) {
                    int r = rq * 4 + e;
                    float s = (float)a2[r] + 0.0078125f * (float)a3[r];
                    float u = fmaf(S_COMB, s, drv[r]);
                    float ex = __expf(2.0f * u);
                    float z  = 1.0f - __fdividef(2.0f, ex + 1.0f);
                    float h  = z * 127.0f;
                    float Q1 = rintf(h);
                    float r1 = (h - Q1) * 128.0f;
                    float Q2 = rintf(r1);
                    d1 |= ((uint)((int)Q1 & 255)) << (8 * e);
                    d2 |= ((uint)((int)Q2 & 255)) << (8 * e);
                }
                int nb  = w * 32 + 8 * rq + 4 * h5;          // n of byte e=0
                int off = abase + (nb ^ axor);               // dword-aligned (xor bits 4..7)
                *(uint*)(zw + off)         = d1;
                *(uint*)(zw + 16384 + off) = d2;
            }
        }
        BARRIER();   // z_{t+1} visible; ring DMA stays in flight across the barrier
    }

    // drain ring, then epilogue: y_{T-1} from z_T (waves 0,1)
    asm volatile("s_waitcnt vmcnt(0)" ::: "memory");
    if (w < 2)
        out_gemm(zsc + (T & 1) * 32768, opb, mbv, w, l, out, b0, T - 1, T);
}

extern "C" void kernel_launch(void* const* d_in, const int* in_sizes, int n_in,
                              void* d_out, int out_size, void* d_ws, size_t ws_size,
                              hipStream_t stream) {
    const float* x  = (const float*)d_in[0];
    const int*   T  = (const int*)d_in[1];
    const float* Iw = (const float*)d_in[2];
    const float* Hw = (const float*)d_in[3];
    const float* Ow = (const float*)d_in[4];
    const float* v  = (const float*)d_in[5];
    const float* m  = (const float*)d_in[6];
    float* out = (float*)d_out;

    uchar* Hpk = (uchar*)d_ws;                   // 16*16*2*1024 = 524288 B
    uchar* Opk = Hpk + 524288;                   // 2*8*1024   =  16384 B

    pack_h<<<dim3(128), dim3(256), 0, stream>>>(Hw, Hpk);
    pack_o<<<dim3(4),   dim3(256), 0, stream>>>(Ow, Opk);
    ctrnn_kernel<<<dim3(256), dim3(1024), 0, stream>>>(x, T, Iw, v, m, Hpk, Opk, out);
}

// Round 15
// 2184.402 us; speedup vs baseline: 1.4601x; 1.4601x over previous
//
#include <hip/hip_runtime.h>

typedef __attribute__((ext_vector_type(4)))  int   int32x4;
typedef __attribute__((ext_vector_type(16))) int   int32x16;
typedef __attribute__((ext_vector_type(16))) float f32x16;
typedef unsigned char uchar;

#define HID 512
#define BT 32
#define OUTN 12

// H/O global scale: |H| ~ N(0, 1/sqrt(512)) => sigma 0.0442, 6.36-sigma = 0.281
#define SH 0.28125f
#define S_COMB (SH / 16129.0f)          // SH / 127^2

// ---- quantize into 2 signed-int8 levels: f ~= SH/127 * (q1 + q2/128)
static __device__ __forceinline__ void quant2(float f, int& q1, int& q2) {
    float h  = fminf(fmaxf(f * (1.0f / SH), -1.0f), 1.0f) * 127.0f;
    float Q1 = rintf(h);
    float r1 = (h - Q1) * 128.0f;
    float Q2 = rintf(r1);
    q1 = (int)Q1; q2 = (int)Q2;
}

// ---- pack H (fp32 [512][512]) into 2 i8 level-streams, A-frag order (A row = n):
//   Hpk[ ((w*16 + ks)*2 + L)*1024 + l*16 + j ] =
//     qL( H[n = w*32 + (l&31)][k = ks*32 + (l>>5)*16 + j] )
__global__ void pack_h(const float* __restrict__ Hw, uchar* __restrict__ Hpk) {
    int t  = blockIdx.x * blockDim.x + threadIdx.x;   // 0..32767
    int l  = t & 63;
    int L  = (t >> 6) & 1;
    int ks = (t >> 7) & 15;
    int w  = t >> 11;                                 // 0..15
    int n  = w * 32 + (l & 31);
    int k0 = ks * 32 + (l >> 5) * 16;
    uint d[4] = {0, 0, 0, 0};
#pragma unroll
    for (int j = 0; j < 16; ++j) {
        int q1, q2;
        quant2(Hw[n * HID + k0 + j], q1, q2);
        int q = L ? q2 : q1;
        d[j >> 2] |= ((uint)(q & 255)) << (8 * (j & 3));
    }
    *(uint4*)(Hpk + (size_t)t * 16) = make_uint4(d[0], d[1], d[2], d[3]);
}

// ---- pack O (fp32 [12][512]) into 2 i8 level-streams (rows padded to 16), for 16x16x64:
//   Opk[ (L*8 + ks)*1024 + l*16 + j ] = qL( O[o = l&15][k = ks*64 + (l>>4)*16 + j] )
__global__ void pack_o(const float* __restrict__ Ow, uchar* __restrict__ Opk) {
    int t  = blockIdx.x * blockDim.x + threadIdx.x;   // 0..1023
    int l  = t & 63;
    int ks = (t >> 6) & 7;
    int L  = t >> 9;                                  // 0..1
    int o  = l & 15;
    int k0 = ks * 64 + (l >> 4) * 16;
    uint d[4] = {0, 0, 0, 0};
#pragma unroll
    for (int j = 0; j < 16; ++j) {
        float f = (o < OUTN) ? Ow[o * HID + k0 + j] : 0.0f;
        int q1, q2;
        quant2(f, q1, q2);
        int q = L ? q2 : q1;
        d[j >> 2] |= ((uint)(q & 255)) << (8 * (j & 3));
    }
    *(uint4*)(Opk + (size_t)t * 16) = make_uint4(d[0], d[1], d[2], d[3]);
}

// z LDS: per buffer 2 level-planes of [32 m][512 n] int8 (16KB each), XOR-swizzled:
//   byte(m, k, L) = L*16384 + m*512 + (k ^ ((m&15)<<4)); buffer stride 32768
// h2-stage LDS (ks 10..15 of each wave's residual plane) at byte 65536:
//   [w][ks-10][l][16B] -> 65536 + ((w*6 + i)*64 + l)*16   (96 KB; total 160 KB)

// ---- output GEMM (2 rotating waves): y = sigmoid(z @ O^T + m), swapped operands:
// D[i=o][j=m]: col = l&15 = m (wave-local batch), row o = (l>>4)*4 + r
// setprio(1): this pair is the per-step straggler (phase3+phase1+phase2) -- give it
// CU issue priority over the 14 bulk waves so the barrier closes sooner.
static __device__ __forceinline__ void out_gemm(const char* zr, const uchar* __restrict__ Opk,
                                                const float* mbv, int wloc, int l,
                                                float* __restrict__ out,
                                                int b0, int trow, int T) {
    __builtin_amdgcn_s_setprio(1);
    int32x4 aA = {0, 0, 0, 0}, aB = {0, 0, 0, 0};
    const int m     = l & 15;
    const int om    = wloc * 16 + m;       // block-local batch row in z planes
    const int obase = om * 512;
    const int oxor  = (om & 15) << 4;      // == m<<4
    const int okb   = (l >> 4) * 16;
    const uchar* op = Opk + (size_t)l * 16;
#pragma unroll
    for (int ks = 0; ks < 8; ++ks) {
        int32x4 o1 = *(const int32x4*)(op + ks * 1024);
        int32x4 o2 = *(const int32x4*)(op + 8192 + ks * 1024);
        int off = obase + ((ks * 64 + okb) ^ oxor);
        int32x4 z1 = *(const int32x4*)(zr + off);
        int32x4 z2 = *(const int32x4*)(zr + 16384 + off);
        aA = __builtin_amdgcn_mfma_i32_16x16x64_i8(o1, z1, aA, 0, 0, 0);
        aB = __builtin_amdgcn_mfma_i32_16x16x64_i8(o1, z2, aB, 0, 0, 0);
        aB = __builtin_amdgcn_mfma_i32_16x16x64_i8(o2, z1, aB, 0, 0, 0);
    }
    if ((l >> 4) < 3) {
        float4 y4;
        float* yp = &y4.x;
#pragma unroll
        for (int r = 0; r < 4; ++r) {
            float logit = mbv[r] + S_COMB * ((float)aA[r] + 0.0078125f * (float)aB[r]);
            yp[r] = __fdividef(1.0f, 1.0f + __expf(-logit));
        }
        *(float4*)(out + ((size_t)(b0 + om) * T + trow) * OUTN + (l >> 4) * 4) = y4;
    }
    __builtin_amdgcn_s_setprio(0);
}

__launch_bounds__(1024)
__global__ void ctrnn_kernel(const float* __restrict__ x,
                             const int*   __restrict__ Tp,
                             const float* __restrict__ Iw,
                             const float* __restrict__ v,
                             const float* __restrict__ mb,
                             const uchar* __restrict__ Hpk,
                             const uchar* __restrict__ Opk,
                             float* __restrict__ out) {
    // 160 KB: 2 z-dbufs (64 KB) + h2 stage for ks 10..15 (96 KB)
    __shared__ uint4 zs4[10240];
    char* zsc = (char*)zs4;

    const int T   = Tp[0];
    const int tid = threadIdx.x;
    const int l   = tid & 63;
    const int w   = tid >> 6;                    // wave 0..15; owns n in [w*32, w*32+32)
    const int b0  = blockIdx.x * BT;

    // zero buf 0 (z_0 = 0 -> both levels 0)
#pragma unroll
    for (int i = 0; i < 2; ++i) zs4[tid + i * 1024] = make_uint4(0, 0, 0, 0);

    // stage h2 (residual plane) for ks 10..15 into LDS (reused all T steps)
#pragma unroll
    for (int i = 0; i < 6; ++i) {
        const uchar* src = Hpk + (size_t)((w * 16 + 10 + i) * 2 + 1) * 1024 + (size_t)l * 16;
        *(uint4*)(zsc + 65536 + (((w * 6 + i) * 64 + l) << 4)) = *(const uint4*)src;
    }

    // drive: drv[r] = x[m]*Iw[n]+v[n], lane owns m = l&31, n = w*32 + nset(r)
    const float xm = x[b0 + (l & 31)];
    f32x16 drv;
#pragma unroll
    for (int r = 0; r < 16; ++r) {
        int n = w * 32 + (r & 3) + 8 * (r >> 2) + 4 * (l >> 5);
        drv[r] = fmaf(xm, Iw[n], v[n]);
    }

    // output bias per lane (loaded by ALL waves: out_gemm rotates across waves)
    float mbv[4] = {0.f, 0.f, 0.f, 0.f};
    if ((l >> 4) < 3) {
#pragma unroll
        for (int r = 0; r < 4; ++r) mbv[r] = mb[(l >> 4) * 4 + r];
    }

    // per-wave packed-H base: ((w*16 + ks)*2 + L)*1024 + l*16
    const uchar* hp = Hpk + (size_t)(w * 16) * 2048 + (size_t)l * 16;

    // staged h2 base in LDS
    const char* h2s = zsc + 65536 + ((w * 6 * 64 + l) << 4);

    // z B-frag addressing: col j = m = l&31, k = ks*32 + (l>>5)*16
    const int am    = l & 31;
    const int abase = am * 512;
    const int axor  = (am & 15) << 4;
    const int akb   = (l >> 5) * 16;

    __syncthreads();

    for (int t = 0; t < T; ++t) {
        const char* zr = zsc + (t & 1) * 32768;
        char*       zw = zsc + ((t & 1) ^ 1) * 32768;

        // ---- phase 3 (2 rotating waves): y_{t-1} from z_t (current read buffer)
        if (((w & 14) == ((t & 7) * 2)) && t > 0)
            out_gemm(zr, Opk, mbv, w & 1, l, out, b0, t - 1, T);

        // ---- phase 1: 3-term i8 MFMA (exact int32 accumulation)
        int32x16 a2 = {0}, a3 = {0};
#pragma unroll 2
        for (int ks = 0; ks < 10; ++ks) {            // h1+h2 streamed from global
            const uchar* hk = hp + (size_t)ks * 2048;
            int32x4 h1 = *(const int32x4*)(hk);
            int32x4 h2 = *(const int32x4*)(hk + 1024);
            int off = abase + ((ks * 32 + akb) ^ axor);
            int32x4 z1 = *(const int32x4*)(zr + off);
            int32x4 z2 = *(const int32x4*)(zr + 16384 + off);
            a2 = __builtin_amdgcn_mfma_i32_32x32x32_i8(h1, z1, a2, 0, 0, 0);
            a3 = __builtin_amdgcn_mfma_i32_32x32x32_i8(h1, z2, a3, 0, 0, 0);
            a3 = __builtin_amdgcn_mfma_i32_32x32x32_i8(h2, z1, a3, 0, 0, 0);
        }
#pragma unroll 2
        for (int i = 0; i < 6; ++i) {                // h1 from global, h2 from LDS stage
            int ks = 10 + i;
            int32x4 h1 = *(const int32x4*)(hp + (size_t)ks * 2048);
            int32x4 h2 = *(const int32x4*)(h2s + i * 1024);
            int off = abase + ((ks * 32 + akb) ^ axor);
            int32x4 z1 = *(const int32x4*)(zr + off);
            int32x4 z2 = *(const int32x4*)(zr + 16384 + off);
            a2 = __builtin_amdgcn_mfma_i32_32x32x32_i8(h1, z1, a2, 0, 0, 0);
            a3 = __builtin_amdgcn_mfma_i32_32x32x32_i8(h1, z2, a3, 0, 0, 0);
            a3 = __builtin_amdgcn_mfma_i32_32x32x32_i8(h2, z1, a3, 0, 0, 0);
        }

        // ---- phase 2: u -> z = tanh(u) -> 2-level i8, packed b32 writes (lane-local)
        {
            const int h5 = l >> 5;
#pragma unroll
            for (int rq = 0; rq < 4; ++rq) {
                uint d1 = 0, d2 = 0;
#pragma unroll
                for (int e = 0; e < 4; ++e) {
                    int r = rq * 4 + e;
                    float s = (float)a2[r] + 0.0078125f * (float)a3[r];
                    float u = fmaf(S_COMB, s, drv[r]);
                    float ex = __expf(2.0f * u);
                    float z  = 1.0f - __fdividef(2.0f, ex + 1.0f);
                    float h  = z * 127.0f;
                    float Q1 = rintf(h);
                    float r1 = (h - Q1) * 128.0f;
                    float Q2 = rintf(r1);
                    d1 |= ((uint)((int)Q1 & 255)) << (8 * e);
                    d2 |= ((uint)((int)Q2 & 255)) << (8 * e);
                }
                int nb  = w * 32 + 8 * rq + 4 * h5;          // n of byte e=0
                int off = abase + (nb ^ axor);               // dword-aligned (xor bits 4..7)
                *(uint*)(zw + off)         = d1;
                *(uint*)(zw + 16384 + off) = d2;
            }
        }
        __syncthreads();   // z_{t+1} complete; all reads of z_t done
    }

    // ---- epilogue: y_{T-1} from z_T (waves 0,1)
    if (w < 2)
        out_gemm(zsc + (T & 1) * 32768, Opk, mbv, w, l, out, b0, T - 1, T);
}

extern "C" void kernel_launch(void* const* d_in, const int* in_sizes, int n_in,
                              void* d_out, int out_size, void* d_ws, size_t ws_size,
                              hipStream_t stream) {
    const float* x  = (const float*)d_in[0];
    const int*   T  = (const int*)d_in[1];
    const float* Iw = (const float*)d_in[2];
    const float* Hw = (const float*)d_in[3];
    const float* Ow = (const float*)d_in[4];
    const float* v  = (const float*)d_in[5];
    const float* m  = (const float*)d_in[6];
    float* out = (float*)d_out;

    uchar* Hpk = (uchar*)d_ws;                   // 16*16*2*1024 = 524288 B
    uchar* Opk = Hpk + 524288;                   // 2*8*1024   =  16384 B

    pack_h<<<dim3(128), dim3(256), 0, stream>>>(Hw, Hpk);
    pack_o<<<dim3(4),   dim3(256), 0, stream>>>(Ow, Opk);
    ctrnn_kernel<<<dim3(256), dim3(1024), 0, stream>>>(x, T, Iw, v, m, Hpk, Opk, out);
}